// Round 1
// baseline (4586.200 us; speedup 1.0000x reference)
//
#include <hip/hip_runtime.h>

// Problem constants
#define BB 32
#define NN 2048
#define FF 3
#define HH 64
#define OUTC 128
#define KK 16
#define BN (BB * NN)   // 65536 points

// ---------------------------------------------------------------------------
// sq[p] = sum_d feat[p][d]^2
// ---------------------------------------------------------------------------
template <int D>
__global__ __launch_bounds__(256) void sq_kernel(const float* __restrict__ f,
                                                 float* __restrict__ sqo) {
    long p = (long)blockIdx.x * 256 + threadIdx.x;   // p < BN
    const float* fp = f + p * D;
    float s = 0.f;
#pragma unroll
    for (int d = 0; d < D; ++d) s = fmaf(fp[d], fp[d], s);
    sqo[p] = s;
}

// ---------------------------------------------------------------------------
// kNN for D=3 (layer 0). One thread per row; candidate tiles of 256 staged in
// LDS as float4 (x, y, z, sq).
// ---------------------------------------------------------------------------
__global__ __launch_bounds__(256) void knn3_kernel(const float* __restrict__ x,
                                                   const float* __restrict__ sq,
                                                   int* __restrict__ idx_out) {
    __shared__ float4 lds_c[256];
    const int b = blockIdx.x >> 3;        // 32 batches
    const int rb = blockIdx.x & 7;        // 8 row-blocks of 256
    const int tid = threadIdx.x;
    const int row = rb * 256 + tid;
    const long pbase = (long)b * NN;

    const float* rp = x + (pbase + row) * 3;
    const float xr0 = rp[0], xr1 = rp[1], xr2 = rp[2];
    const float sqr = sq[pbase + row];

    float dist[KK];
    int idx[KK];
#pragma unroll
    for (int j = 0; j < KK; ++j) { dist[j] = 3.0e38f; idx[j] = 0; }

    for (int t = 0; t < NN / 256; ++t) {
        __syncthreads();
        {
            const int m = t * 256 + tid;
            const float* cp = x + (pbase + m) * 3;
            lds_c[tid] = make_float4(cp[0], cp[1], cp[2], sq[pbase + m]);
        }
        __syncthreads();
        for (int c = 0; c < 256; ++c) {
            float4 v = lds_c[c];
            float acc = 0.f;
            acc = fmaf(xr0, v.x, acc);
            acc = fmaf(xr1, v.y, acc);
            acc = fmaf(xr2, v.z, acc);
            float d2 = fmaf(-2.0f, acc, sqr + v.w);
            int m = t * 256 + c;
            if (d2 < dist[KK - 1]) {
                dist[KK - 1] = d2; idx[KK - 1] = m;
#pragma unroll
                for (int j = KK - 1; j > 0; --j) {
                    if (dist[j] < dist[j - 1]) {
                        float tf = dist[j]; dist[j] = dist[j - 1]; dist[j - 1] = tf;
                        int ti = idx[j]; idx[j] = idx[j - 1]; idx[j - 1] = ti;
                    }
                }
            }
        }
    }
    int* op = idx_out + (pbase + row) * KK;
#pragma unroll
    for (int j = 0; j < KK; ++j) op[j] = idx[j];
}

// ---------------------------------------------------------------------------
// kNN for D=64 (layers 1,2). One thread per row, row vector in VGPRs,
// candidate tiles of 64 rows staged in LDS.
// ---------------------------------------------------------------------------
__global__ __launch_bounds__(256) void knn64_kernel(const float* __restrict__ feat,
                                                    const float* __restrict__ sq,
                                                    int* __restrict__ idx_out) {
    __shared__ float lds_col[64 * 64];
    __shared__ float lds_sq[64];
    const int b = blockIdx.x >> 3;
    const int rb = blockIdx.x & 7;
    const int tid = threadIdx.x;
    const int row = rb * 256 + tid;
    const long pbase = (long)b * NN;

    float xr[64];
    {
        const float4* rp = (const float4*)(feat + (pbase + row) * 64);
#pragma unroll
        for (int i = 0; i < 16; ++i) {
            float4 v = rp[i];
            xr[4 * i + 0] = v.x; xr[4 * i + 1] = v.y;
            xr[4 * i + 2] = v.z; xr[4 * i + 3] = v.w;
        }
    }
    const float sqr = sq[pbase + row];

    float dist[KK];
    int idx[KK];
#pragma unroll
    for (int j = 0; j < KK; ++j) { dist[j] = 3.0e38f; idx[j] = 0; }

    for (int t = 0; t < NN / 64; ++t) {
        __syncthreads();
        {
            const float4* cp = (const float4*)(feat + (pbase + (long)t * 64) * 64);
            float4* dst = (float4*)lds_col;
#pragma unroll
            for (int i = 0; i < 4; ++i) dst[tid + 256 * i] = cp[tid + 256 * i];
            if (tid < 64) lds_sq[tid] = sq[pbase + t * 64 + tid];
        }
        __syncthreads();
        for (int c = 0; c < 64; ++c) {
            const float4* cv = (const float4*)(lds_col + c * 64);
            float acc = 0.f;
#pragma unroll
            for (int dq = 0; dq < 16; ++dq) {
                float4 v = cv[dq];
                acc = fmaf(xr[4 * dq + 0], v.x, acc);
                acc = fmaf(xr[4 * dq + 1], v.y, acc);
                acc = fmaf(xr[4 * dq + 2], v.z, acc);
                acc = fmaf(xr[4 * dq + 3], v.w, acc);
            }
            float d2 = fmaf(-2.0f, acc, sqr + lds_sq[c]);
            int m = t * 64 + c;
            if (d2 < dist[KK - 1]) {
                dist[KK - 1] = d2; idx[KK - 1] = m;
#pragma unroll
                for (int j = KK - 1; j > 0; --j) {
                    if (dist[j] < dist[j - 1]) {
                        float tf = dist[j]; dist[j] = dist[j - 1]; dist[j - 1] = tf;
                        int ti = idx[j]; idx[j] = idx[j - 1]; idx[j - 1] = ti;
                    }
                }
            }
        }
    }
    int* op = idx_out + (pbase + row) * KK;
#pragma unroll
    for (int j = 0; j < KK; ++j) op[j] = idx[j];
}

// ---------------------------------------------------------------------------
// P[p][h] = b1[h] + sum_d f[p][d] * (w1[d][h] - w1[D+d][h])
// Q[p][h] =         sum_d f[p][d] *  w1[D+d][h]
// ---------------------------------------------------------------------------
template <int D>
__global__ __launch_bounds__(256) void pq_kernel(const float* __restrict__ feat,
                                                 const float* __restrict__ w1,
                                                 const float* __restrict__ b1,
                                                 float* __restrict__ P,
                                                 float* __restrict__ Q) {
    const int tid = threadIdx.x;
    const int h = tid & 63;
    const int pl = tid >> 6;
    const long p = (long)blockIdx.x * 4 + pl;   // p < BN
    const float* fp = feat + p * D;
    float accp = 0.f, accq = 0.f;
#pragma unroll
    for (int d = 0; d < D; ++d) {
        float fv = fp[d];
        float wa = w1[d * HH + h];
        float wb = w1[(D + d) * HH + h];
        accp = fmaf(fv, wa - wb, accp);
        accq = fmaf(fv, wb, accq);
    }
    P[p * HH + h] = accp + b1[h];
    Q[p * HH + h] = accq;
}

// ---------------------------------------------------------------------------
// R[p] = (1/K) sum_k relu(P[p] + Q[j_k]);  out[p] = R[p] @ wo + bo
// ---------------------------------------------------------------------------
__global__ __launch_bounds__(256) void gather_mlp_kernel(const float* __restrict__ P,
                                                         const float* __restrict__ Q,
                                                         const int* __restrict__ idx,
                                                         const float* __restrict__ wo,
                                                         const float* __restrict__ bo,
                                                         float* __restrict__ out) {
    __shared__ float Rl[4][HH];
    const int tid = threadIdx.x;
    const int h = tid & 63;
    const int pl = tid >> 6;
    const long p = (long)blockIdx.x * 4 + pl;
    const long bbase = (p >> 11) << 11;    // batch base point index
    const float Pv = P[p * HH + h];
    const int* ip = idx + p * KK;
    float acc = 0.f;
#pragma unroll
    for (int k = 0; k < KK; ++k) {
        int j = ip[k];
        float qv = Q[(bbase + j) * HH + h];
        acc += fmaxf(Pv + qv, 0.f);
    }
    acc *= (1.f / KK);
    Rl[pl][h] = acc;
    __syncthreads();
    float o = bo[h];
#pragma unroll
    for (int l = 0; l < HH; ++l) o = fmaf(Rl[pl][l], wo[l * HH + h], o);
    out[p * HH + h] = o;
}

// ---------------------------------------------------------------------------
// g[b] = mean_n feat[b,n,:];  out[b] = relu(g@fw1+fb1)@fw2+fb2
// ---------------------------------------------------------------------------
__global__ __launch_bounds__(256) void pool_head_kernel(const float* __restrict__ feat,
                                                        const float* __restrict__ fw1,
                                                        const float* __restrict__ fb1,
                                                        const float* __restrict__ fw2,
                                                        const float* __restrict__ fb2,
                                                        float* __restrict__ out) {
    __shared__ float part[4][HH];
    __shared__ float g[HH];
    __shared__ float tl[HH];
    const int b = blockIdx.x;
    const int tid = threadIdx.x;
    const int h = tid & 63;
    const int ch = tid >> 6;
    float s = 0.f;
    const float* fp = feat + ((long)b * NN + ch * 512) * HH + h;
    for (int n = 0; n < 512; ++n) s += fp[(long)n * HH];
    part[ch][h] = s;
    __syncthreads();
    if (tid < HH) g[h] = (part[0][h] + part[1][h] + part[2][h] + part[3][h]) * (1.f / NN);
    __syncthreads();
    if (tid < HH) {
        float a = fb1[h];
#pragma unroll
        for (int l = 0; l < HH; ++l) a = fmaf(g[l], fw1[l * HH + h], a);
        tl[h] = fmaxf(a, 0.f);
    }
    __syncthreads();
    if (tid < OUTC) {
        float o = fb2[tid];
#pragma unroll
        for (int l = 0; l < HH; ++l) o = fmaf(tl[l], fw2[l * OUTC + tid], o);
        out[(long)b * OUTC + tid] = o;
    }
}

// ---------------------------------------------------------------------------
extern "C" void kernel_launch(void* const* d_in, const int* in_sizes, int n_in,
                              void* d_out, int out_size, void* d_ws, size_t ws_size,
                              hipStream_t stream) {
    const float* x    = (const float*)d_in[0];
    const float* w1_0 = (const float*)d_in[1];
    const float* b1_0 = (const float*)d_in[2];
    const float* wo_0 = (const float*)d_in[3];
    const float* bo_0 = (const float*)d_in[4];
    const float* w1_1 = (const float*)d_in[5];
    const float* b1_1 = (const float*)d_in[6];
    const float* wo_1 = (const float*)d_in[7];
    const float* bo_1 = (const float*)d_in[8];
    const float* w1_2 = (const float*)d_in[9];
    const float* b1_2 = (const float*)d_in[10];
    const float* wo_2 = (const float*)d_in[11];
    const float* bo_2 = (const float*)d_in[12];
    const float* fw1  = (const float*)d_in[13];
    const float* fb1  = (const float*)d_in[14];
    const float* fw2  = (const float*)d_in[15];
    const float* fb2  = (const float*)d_in[16];
    float* out = (float*)d_out;

    // workspace layout (floats)
    float* featA = (float*)d_ws;
    float* featB = featA + (long)BN * HH;
    float* Pb    = featB + (long)BN * HH;
    float* Qb    = Pb + (long)BN * HH;
    float* sqb   = Qb + (long)BN * HH;
    int*   idxb  = (int*)(sqb + BN);

    // ---- layer 0 (D=3) ----
    sq_kernel<3><<<BN / 256, 256, 0, stream>>>(x, sqb);
    knn3_kernel<<<256, 256, 0, stream>>>(x, sqb, idxb);
    pq_kernel<3><<<BN / 4, 256, 0, stream>>>(x, w1_0, b1_0, Pb, Qb);
    gather_mlp_kernel<<<BN / 4, 256, 0, stream>>>(Pb, Qb, idxb, wo_0, bo_0, featA);

    // ---- layer 1 (D=64) ----
    sq_kernel<64><<<BN / 256, 256, 0, stream>>>(featA, sqb);
    knn64_kernel<<<256, 256, 0, stream>>>(featA, sqb, idxb);
    pq_kernel<64><<<BN / 4, 256, 0, stream>>>(featA, w1_1, b1_1, Pb, Qb);
    gather_mlp_kernel<<<BN / 4, 256, 0, stream>>>(Pb, Qb, idxb, wo_1, bo_1, featB);

    // ---- layer 2 (D=64) ----
    sq_kernel<64><<<BN / 256, 256, 0, stream>>>(featB, sqb);
    knn64_kernel<<<256, 256, 0, stream>>>(featB, sqb, idxb);
    pq_kernel<64><<<BN / 4, 256, 0, stream>>>(featB, w1_2, b1_2, Pb, Qb);
    gather_mlp_kernel<<<BN / 4, 256, 0, stream>>>(Pb, Qb, idxb, wo_2, bo_2, featA);

    // ---- pool + head ----
    pool_head_kernel<<<BB, 256, 0, stream>>>(featA, fw1, fb1, fw2, fb2, out);
}

// Round 2
// 3413.449 us; speedup vs baseline: 1.3436x; 1.3436x over previous
//
#include <hip/hip_runtime.h>

// Problem constants
#define BB 32
#define NN 2048
#define FF 3
#define HH 64
#define OUTC 128
#define KK 16
#define BN (BB * NN)   // 65536 points

#define SPLIT 2
#define CSZ (NN / SPLIT)   // 1024 candidates per partial scan

// ---------------------------------------------------------------------------
// sq[p] = sum_d feat[p][d]^2
// ---------------------------------------------------------------------------
template <int D>
__global__ __launch_bounds__(256) void sq_kernel(const float* __restrict__ f,
                                                 float* __restrict__ sqo) {
    long p = (long)blockIdx.x * 256 + threadIdx.x;   // p < BN
    const float* fp = f + p * D;
    float s = 0.f;
#pragma unroll
    for (int d = 0; d < D; ++d) s = fmaf(fp[d], fp[d], s);
    sqo[p] = s;
}

// ---------------------------------------------------------------------------
// kNN for D=3 (layer 0). One thread per row; candidate tiles of 256 staged in
// LDS as float4 (x, y, z, sq).
// ---------------------------------------------------------------------------
__global__ __launch_bounds__(256) void knn3_kernel(const float* __restrict__ x,
                                                   const float* __restrict__ sq,
                                                   int* __restrict__ idx_out) {
    __shared__ float4 lds_c[256];
    const int b = blockIdx.x >> 3;        // 32 batches
    const int rb = blockIdx.x & 7;        // 8 row-blocks of 256
    const int tid = threadIdx.x;
    const int row = rb * 256 + tid;
    const long pbase = (long)b * NN;

    const float* rp = x + (pbase + row) * 3;
    const float xr0 = rp[0], xr1 = rp[1], xr2 = rp[2];
    const float sqr = sq[pbase + row];

    float dist[KK];
    int idx[KK];
#pragma unroll
    for (int j = 0; j < KK; ++j) { dist[j] = 3.0e38f; idx[j] = 0; }

    for (int t = 0; t < NN / 256; ++t) {
        __syncthreads();
        {
            const int m = t * 256 + tid;
            const float* cp = x + (pbase + m) * 3;
            lds_c[tid] = make_float4(cp[0], cp[1], cp[2], sq[pbase + m]);
        }
        __syncthreads();
        for (int c = 0; c < 256; ++c) {
            float4 v = lds_c[c];
            float acc = 0.f;
            acc = fmaf(xr0, v.x, acc);
            acc = fmaf(xr1, v.y, acc);
            acc = fmaf(xr2, v.z, acc);
            float d2 = fmaf(-2.0f, acc, sqr + v.w);
            int m = t * 256 + c;
            if (d2 < dist[KK - 1]) {
                dist[KK - 1] = d2; idx[KK - 1] = m;
#pragma unroll
                for (int j = KK - 1; j > 0; --j) {
                    if (dist[j] < dist[j - 1]) {
                        float tf = dist[j]; dist[j] = dist[j - 1]; dist[j - 1] = tf;
                        int ti = idx[j]; idx[j] = idx[j - 1]; idx[j - 1] = ti;
                    }
                }
            }
        }
    }
    int* op = idx_out + (pbase + row) * KK;
#pragma unroll
    for (int j = 0; j < KK; ++j) op[j] = idx[j];
}

// ---------------------------------------------------------------------------
// kNN partial scan for D=64 (layers 1,2). One thread per row, row in VGPRs.
// Candidate vectors are wave-uniform -> scalar (s_load) reads from global,
// no LDS at all. Each block scans CSZ candidates; partial sorted top-16
// (dist,idx) written to pdist/pidx for the merge kernel.
// ---------------------------------------------------------------------------
__global__ __launch_bounds__(256) void knn64_part_kernel(const float* __restrict__ feat,
                                                         const float* __restrict__ sq,
                                                         float* __restrict__ pdist,
                                                         int* __restrict__ pidx) {
    const int s = blockIdx.x & (SPLIT - 1);
    const int rbb = blockIdx.x / SPLIT;
    const int b = rbb >> 3;
    const int rb = rbb & 7;
    const int tid = threadIdx.x;
    const int row = rb * 256 + tid;
    const long pbase = (long)b * NN;

    float xr[64];
    {
        const float4* rp = (const float4*)(feat + (pbase + row) * 64);
#pragma unroll
        for (int i = 0; i < 16; ++i) {
            float4 v = rp[i];
            xr[4 * i + 0] = v.x; xr[4 * i + 1] = v.y;
            xr[4 * i + 2] = v.z; xr[4 * i + 3] = v.w;
        }
    }
    const float sqr = sq[pbase + row];

    float dist[KK];
    int idx[KK];
#pragma unroll
    for (int j = 0; j < KK; ++j) { dist[j] = 3.0e38f; idx[j] = 0; }

    const float* cb = feat + (pbase + (long)s * CSZ) * 64;   // wave-uniform base
    const float* sqc = sq + pbase + s * CSZ;

    for (int c = 0; c < CSZ; ++c) {
        const float* cp = cb + (long)c * 64;                 // uniform address
        float a0 = 0.f, a1 = 0.f, a2 = 0.f, a3 = 0.f;
#pragma unroll
        for (int d = 0; d < 64; d += 4) {
            a0 = fmaf(xr[d + 0], cp[d + 0], a0);
            a1 = fmaf(xr[d + 1], cp[d + 1], a1);
            a2 = fmaf(xr[d + 2], cp[d + 2], a2);
            a3 = fmaf(xr[d + 3], cp[d + 3], a3);
        }
        float acc = (a0 + a1) + (a2 + a3);
        float d2 = fmaf(-2.0f, acc, sqr + sqc[c]);
        int m = s * CSZ + c;
        if (d2 < dist[KK - 1]) {
            dist[KK - 1] = d2; idx[KK - 1] = m;
#pragma unroll
            for (int j = KK - 1; j > 0; --j) {
                if (dist[j] < dist[j - 1]) {
                    float tf = dist[j]; dist[j] = dist[j - 1]; dist[j - 1] = tf;
                    int ti = idx[j]; idx[j] = idx[j - 1]; idx[j - 1] = ti;
                }
            }
        }
    }

    float* dp = pdist + ((pbase + row) * SPLIT + s) * KK;
    int* ip = pidx + ((pbase + row) * SPLIT + s) * KK;
#pragma unroll
    for (int j = 0; j < KK; ++j) { dp[j] = dist[j]; ip[j] = idx[j]; }
}

// ---------------------------------------------------------------------------
// Merge SPLIT sorted partial top-16 lists -> final top-16 indices per row.
// Tie -> list with lower candidate indices (list 0), matching lax.top_k.
// ---------------------------------------------------------------------------
__global__ __launch_bounds__(256) void knn_merge_kernel(const float* __restrict__ pdist,
                                                        const int* __restrict__ pidx,
                                                        int* __restrict__ idx_out) {
    long p = (long)blockIdx.x * 256 + threadIdx.x;
    const float* dp = pdist + p * (SPLIT * KK);
    const int* ip = pidx + p * (SPLIT * KK);
    float d0[KK], d1[KK];
    int i0[KK], i1[KK];
#pragma unroll
    for (int j = 0; j < KK; ++j) {
        d0[j] = dp[j]; d1[j] = dp[KK + j];
        i0[j] = ip[j]; i1[j] = ip[KK + j];
    }
    int* op = idx_out + p * KK;
    int ia = 0, ib = 0;
#pragma unroll
    for (int j = 0; j < KK; ++j) {
        float da = d0[ia], db = d1[ib];
        bool takeA = (da <= db);
        op[j] = takeA ? i0[ia] : i1[ib];
        ia += takeA ? 1 : 0;
        ib += takeA ? 0 : 1;
    }
}

// ---------------------------------------------------------------------------
// P[p][h] = b1[h] + sum_d f[p][d] * (w1[d][h] - w1[D+d][h])
// Q[p][h] =         sum_d f[p][d] *  w1[D+d][h]
// ---------------------------------------------------------------------------
template <int D>
__global__ __launch_bounds__(256) void pq_kernel(const float* __restrict__ feat,
                                                 const float* __restrict__ w1,
                                                 const float* __restrict__ b1,
                                                 float* __restrict__ P,
                                                 float* __restrict__ Q) {
    const int tid = threadIdx.x;
    const int h = tid & 63;
    const int pl = tid >> 6;
    const long p = (long)blockIdx.x * 4 + pl;   // p < BN
    const float* fp = feat + p * D;
    float accp = 0.f, accq = 0.f;
#pragma unroll
    for (int d = 0; d < D; ++d) {
        float fv = fp[d];
        float wa = w1[d * HH + h];
        float wb = w1[(D + d) * HH + h];
        accp = fmaf(fv, wa - wb, accp);
        accq = fmaf(fv, wb, accq);
    }
    P[p * HH + h] = accp + b1[h];
    Q[p * HH + h] = accq;
}

// ---------------------------------------------------------------------------
// R[p] = (1/K) sum_k relu(P[p] + Q[j_k]);  out[p] = R[p] @ wo + bo
// ---------------------------------------------------------------------------
__global__ __launch_bounds__(256) void gather_mlp_kernel(const float* __restrict__ P,
                                                         const float* __restrict__ Q,
                                                         const int* __restrict__ idx,
                                                         const float* __restrict__ wo,
                                                         const float* __restrict__ bo,
                                                         float* __restrict__ out) {
    __shared__ float Rl[4][HH];
    const int tid = threadIdx.x;
    const int h = tid & 63;
    const int pl = tid >> 6;
    const long p = (long)blockIdx.x * 4 + pl;
    const long bbase = (p >> 11) << 11;    // batch base point index
    const float Pv = P[p * HH + h];
    const int* ip = idx + p * KK;
    float acc = 0.f;
#pragma unroll
    for (int k = 0; k < KK; ++k) {
        int j = ip[k];
        float qv = Q[(bbase + j) * HH + h];
        acc += fmaxf(Pv + qv, 0.f);
    }
    acc *= (1.f / KK);
    Rl[pl][h] = acc;
    __syncthreads();
    float o = bo[h];
#pragma unroll
    for (int l = 0; l < HH; ++l) o = fmaf(Rl[pl][l], wo[l * HH + h], o);
    out[p * HH + h] = o;
}

// ---------------------------------------------------------------------------
// g[b] = mean_n feat[b,n,:];  out[b] = relu(g@fw1+fb1)@fw2+fb2
// ---------------------------------------------------------------------------
__global__ __launch_bounds__(256) void pool_head_kernel(const float* __restrict__ feat,
                                                        const float* __restrict__ fw1,
                                                        const float* __restrict__ fb1,
                                                        const float* __restrict__ fw2,
                                                        const float* __restrict__ fb2,
                                                        float* __restrict__ out) {
    __shared__ float part[4][HH];
    __shared__ float g[HH];
    __shared__ float tl[HH];
    const int b = blockIdx.x;
    const int tid = threadIdx.x;
    const int h = tid & 63;
    const int ch = tid >> 6;
    float s = 0.f;
    const float* fp = feat + ((long)b * NN + ch * 512) * HH + h;
    for (int n = 0; n < 512; ++n) s += fp[(long)n * HH];
    part[ch][h] = s;
    __syncthreads();
    if (tid < HH) g[h] = (part[0][h] + part[1][h] + part[2][h] + part[3][h]) * (1.f / NN);
    __syncthreads();
    if (tid < HH) {
        float a = fb1[h];
#pragma unroll
        for (int l = 0; l < HH; ++l) a = fmaf(g[l], fw1[l * HH + h], a);
        tl[h] = fmaxf(a, 0.f);
    }
    __syncthreads();
    if (tid < OUTC) {
        float o = fb2[tid];
#pragma unroll
        for (int l = 0; l < HH; ++l) o = fmaf(tl[l], fw2[l * OUTC + tid], o);
        out[(long)b * OUTC + tid] = o;
    }
}

// ---------------------------------------------------------------------------
extern "C" void kernel_launch(void* const* d_in, const int* in_sizes, int n_in,
                              void* d_out, int out_size, void* d_ws, size_t ws_size,
                              hipStream_t stream) {
    const float* x    = (const float*)d_in[0];
    const float* w1_0 = (const float*)d_in[1];
    const float* b1_0 = (const float*)d_in[2];
    const float* wo_0 = (const float*)d_in[3];
    const float* bo_0 = (const float*)d_in[4];
    const float* w1_1 = (const float*)d_in[5];
    const float* b1_1 = (const float*)d_in[6];
    const float* wo_1 = (const float*)d_in[7];
    const float* bo_1 = (const float*)d_in[8];
    const float* w1_2 = (const float*)d_in[9];
    const float* b1_2 = (const float*)d_in[10];
    const float* wo_2 = (const float*)d_in[11];
    const float* bo_2 = (const float*)d_in[12];
    const float* fw1  = (const float*)d_in[13];
    const float* fb1  = (const float*)d_in[14];
    const float* fw2  = (const float*)d_in[15];
    const float* fb2  = (const float*)d_in[16];
    float* out = (float*)d_out;

    // workspace layout (floats)
    float* featA = (float*)d_ws;
    float* featB = featA + (long)BN * HH;
    float* Pb    = featB + (long)BN * HH;
    float* Qb    = Pb + (long)BN * HH;
    float* sqb   = Qb + (long)BN * HH;
    int*   idxb  = (int*)(sqb + BN);

    // partial top-k buffers live in Pb/Qb (only used before pq_kernel writes them)
    float* pdist = Pb;
    int*   pidx  = (int*)Qb;

    // ---- layer 0 (D=3) ----
    sq_kernel<3><<<BN / 256, 256, 0, stream>>>(x, sqb);
    knn3_kernel<<<256, 256, 0, stream>>>(x, sqb, idxb);
    pq_kernel<3><<<BN / 4, 256, 0, stream>>>(x, w1_0, b1_0, Pb, Qb);
    gather_mlp_kernel<<<BN / 4, 256, 0, stream>>>(Pb, Qb, idxb, wo_0, bo_0, featA);

    // ---- layer 1 (D=64) ----
    sq_kernel<64><<<BN / 256, 256, 0, stream>>>(featA, sqb);
    knn64_part_kernel<<<256 * SPLIT, 256, 0, stream>>>(featA, sqb, pdist, pidx);
    knn_merge_kernel<<<BN / 256, 256, 0, stream>>>(pdist, pidx, idxb);
    pq_kernel<64><<<BN / 4, 256, 0, stream>>>(featA, w1_1, b1_1, Pb, Qb);
    gather_mlp_kernel<<<BN / 4, 256, 0, stream>>>(Pb, Qb, idxb, wo_1, bo_1, featB);

    // ---- layer 2 (D=64) ----
    sq_kernel<64><<<BN / 256, 256, 0, stream>>>(featB, sqb);
    knn64_part_kernel<<<256 * SPLIT, 256, 0, stream>>>(featB, sqb, pdist, pidx);
    knn_merge_kernel<<<BN / 256, 256, 0, stream>>>(pdist, pidx, idxb);
    pq_kernel<64><<<BN / 4, 256, 0, stream>>>(featB, w1_2, b1_2, Pb, Qb);
    gather_mlp_kernel<<<BN / 4, 256, 0, stream>>>(Pb, Qb, idxb, wo_2, bo_2, featB);

    // ---- pool + head ----
    pool_head_kernel<<<BB, 256, 0, stream>>>(featB, fw1, fb1, fw2, fb2, out);
}